// Round 12
// baseline (232.955 us; speedup 1.0000x reference)
//
#include <hip/hip_runtime.h>
#include <hip/hip_bf16.h>

typedef __attribute__((ext_vector_type(8))) __bf16 bf16x8;
typedef __attribute__((ext_vector_type(4))) __bf16 bf16x4;
typedef __attribute__((ext_vector_type(4))) float f32x4;

#define IN_FEAT 128
#define OUT_FEAT 128
#define N_REL 16
#define TILE_M 64
#define CHUNK_T 8

// ---------------- merged prep ----------------
// blocks [0,64):          W fp32 [r][k][n] -> bf16 [r][n][k], LDS-tiled
// blocks [64,64+cvtb):    X fp32 -> bf16 (8 elems/thread, coalesced)
// blocks [64+cvtb, ...):  relation hist (LDS-agg) + target hist (direct atomics)
__global__ __launch_bounds__(256) void prep_kernel(
        const float* __restrict__ w, __bf16* __restrict__ wt,
        const float* __restrict__ x, __bf16* __restrict__ xb, int nX, int cvtb,
        const int* __restrict__ etype, const int* __restrict__ etgt, int n,
        int* __restrict__ cnt_rel, int* __restrict__ cnt_tgt) {
    __shared__ __bf16 tile[32 * 136];
    __shared__ int h[N_REL];
    int t = threadIdx.x;
    if (blockIdx.x < 64) {
        int r = blockIdx.x >> 2;
        int n0 = (blockIdx.x & 3) * 32;
        const float* W = w + (size_t)r * IN_FEAT * OUT_FEAT;
        __bf16* T = wt + (size_t)r * IN_FEAT * OUT_FEAT;
        #pragma unroll
        for (int it = 0; it < 16; ++it) {
            int idx = t + it * 256;
            int k = idx >> 5, dn = idx & 31;
            tile[dn * 136 + k] = (__bf16)W[k * OUT_FEAT + n0 + dn];
        }
        __syncthreads();
        #pragma unroll
        for (int it = 0; it < 2; ++it) {
            int idx = t + it * 256;
            int nn = idx >> 4, c = idx & 15;
            bf16x8 v = *(const bf16x8*)(&tile[nn * 136 + c * 8]);
            *(bf16x8*)(T + (size_t)(n0 + nn) * IN_FEAT + c * 8) = v;
        }
    } else if (blockIdx.x < 64 + cvtb) {
        int i = ((blockIdx.x - 64) * 256 + t) * 8;
        if (i < nX) {
            const float4* xr = (const float4*)(x + i);
            float4 f0 = xr[0], f1 = xr[1];
            bf16x8 o = { (__bf16)f0.x, (__bf16)f0.y, (__bf16)f0.z, (__bf16)f0.w,
                         (__bf16)f1.x, (__bf16)f1.y, (__bf16)f1.z, (__bf16)f1.w };
            *(bf16x8*)(xb + i) = o;
        }
    } else {
        if (t < N_REL) h[t] = 0;
        __syncthreads();
        int stride = (gridDim.x - 64 - cvtb) * blockDim.x;
        for (int i = (blockIdx.x - 64 - cvtb) * blockDim.x + t; i < n; i += stride) {
            atomicAdd(&h[etype[i]], 1);
            if (cnt_tgt) atomicAdd(&cnt_tgt[etgt[i]], 1);
        }
        __syncthreads();
        if (t < N_REL) atomicAdd(&cnt_rel[t], h[t]);
    }
}

// standalone hist + prefix (fallback path only)
__global__ void hist_kernel(const int* __restrict__ etype, int n, int* __restrict__ cnt_rel) {
    __shared__ int h[N_REL];
    if (threadIdx.x < N_REL) h[threadIdx.x] = 0;
    __syncthreads();
    for (int i = blockIdx.x * blockDim.x + threadIdx.x; i < n; i += gridDim.x * blockDim.x)
        atomicAdd(&h[etype[i]], 1);
    __syncthreads();
    if (threadIdx.x < N_REL) atomicAdd(&cnt_rel[threadIdx.x], h[threadIdx.x]);
}
__global__ void prefix_kernel(const int* __restrict__ cnt, int* __restrict__ meta) {
    if (threadIdx.x == 0) {
        int off = 0, toff = 0;
        for (int r = 0; r < N_REL; ++r) {
            meta[r] = off; meta[32 + r] = toff; meta[64 + r] = off;
            off += cnt[r];
            toff += (cnt[r] + TILE_M - 1) / TILE_M;
        }
        meta[16] = off; meta[48] = toff;
    }
}

// ---------------- SINGLE-dispatch exclusive scan over N_NODES tgt counts ----------------
// Replaces scanA+scanC2: each block computes its chunk base by directly summing all
// preceding cnt_tgt entries (<=50K coalesced L2-resident loads across 256 threads,
// ~196 iters worst case). Saves one graph node (R2..R11 ledger: aux residual pinned
// at ~165 us across wildly different aux content => ~13 us fixed cost per node).
__global__ void scanC3_kernel(const int* __restrict__ cnt, int n,
                              const int* __restrict__ cnt_rel, int* __restrict__ meta,
                              int* __restrict__ base, int* __restrict__ cursor) {
    __shared__ int s[256];
    __shared__ int sbase;
    int t = threadIdx.x;
    int start = blockIdx.x * 256;
    int pb = 0;
    for (int j = t; j < start; j += 256) pb += cnt[j];
    s[t] = pb;
    __syncthreads();
    for (int off = 128; off > 0; off >>= 1) {
        if (t < off) s[t] += s[t + off];
        __syncthreads();
    }
    if (t == 0) sbase = s[0];
    __syncthreads();
    int blockbase = sbase;
    __syncthreads();
    int i = start + t;
    int v = (i < n) ? cnt[i] : 0;
    s[t] = v;
    __syncthreads();
    for (int off = 1; off < 256; off <<= 1) {
        int x = (t >= off) ? s[t - off] : 0;
        __syncthreads();
        s[t] += x;
        __syncthreads();
    }
    int b = blockbase + s[t] - v;
    if (i < n) { base[i] = b; cursor[i] = b; }
    if (blockIdx.x == 0 && t == 0) {
        int off = 0, toff = 0;
        for (int r = 0; r < N_REL; ++r) {
            meta[r] = off; meta[32 + r] = toff; meta[64 + r] = off;
            off += cnt_rel[r];
            toff += (cnt_rel[r] + TILE_M - 1) / TILE_M;
        }
        meta[16] = off; meta[48] = toff;
    }
}

// ---------------- bucket scatter by relation, assigning tgt-sorted msg slots ----------------
#define SCATTER_EPT 2
#define SCATTER_CHUNK (256 * SCATTER_EPT)
__global__ __launch_bounds__(256) void scatter_slot_kernel(
        const int* __restrict__ esrc, const int* __restrict__ etgt,
        const int* __restrict__ etype, int n,
        int* __restrict__ cursor_rel, int* __restrict__ cursor_tgt,
        int* __restrict__ bsrc, int* __restrict__ bslot) {
    __shared__ int lcnt[N_REL];
    __shared__ int lbase[N_REL];
    int t = threadIdx.x;
    if (t < N_REL) lcnt[t] = 0;
    __syncthreads();
    int base = blockIdx.x * SCATTER_CHUNK;
    int rj[SCATTER_EPT], offj[SCATTER_EPT];
    #pragma unroll
    for (int j = 0; j < SCATTER_EPT; ++j) {
        int i = base + j * 256 + t;
        if (i < n) {
            int r = etype[i];
            rj[j] = r;
            offj[j] = atomicAdd(&lcnt[r], 1);
        } else rj[j] = -1;
    }
    __syncthreads();
    if (t < N_REL) lbase[t] = atomicAdd(&cursor_rel[t], lcnt[t]);
    __syncthreads();
    #pragma unroll
    for (int j = 0; j < SCATTER_EPT; ++j) {
        if (rj[j] >= 0) {
            int i = base + j * 256 + t;
            int p = lbase[rj[j]] + offj[j];
            bsrc[p] = esrc[i];
            bslot[p] = atomicAdd(&cursor_tgt[etgt[i]], 1);
        }
    }
}

// fallback scatter (bucket by relation, carry tgt)
__global__ __launch_bounds__(256) void scatter_kernel(
        const int* __restrict__ esrc, const int* __restrict__ etgt,
        const int* __restrict__ etype, int n,
        int* __restrict__ cursor,
        int* __restrict__ bsrc, int* __restrict__ btgt) {
    __shared__ int lcnt[N_REL];
    __shared__ int lbase[N_REL];
    int t = threadIdx.x;
    if (t < N_REL) lcnt[t] = 0;
    __syncthreads();
    int base = blockIdx.x * SCATTER_CHUNK;
    int rj[SCATTER_EPT], offj[SCATTER_EPT];
    #pragma unroll
    for (int j = 0; j < SCATTER_EPT; ++j) {
        int i = base + j * 256 + t;
        if (i < n) {
            int r = etype[i];
            rj[j] = r;
            offj[j] = atomicAdd(&lcnt[r], 1);
        } else rj[j] = -1;
    }
    __syncthreads();
    if (t < N_REL) lbase[t] = atomicAdd(&cursor[t], lcnt[t]);
    __syncthreads();
    #pragma unroll
    for (int j = 0; j < SCATTER_EPT; ++j) {
        if (rj[j] >= 0) {
            int i = base + j * 256 + t;
            int p = lbase[rj[j]] + offj[j];
            bsrc[p] = esrc[i];
            btgt[p] = etgt[i];
        }
    }
}

// ---------------- main GEMM v8 (R11, unchanged): A direct-to-register, B-only LDS ------
__global__ __launch_bounds__(256, 4) void gemm_msg8_kernel(
    const __bf16* __restrict__ Xb,    // bf16 [N_NODES][128]
    const __bf16* __restrict__ Wt,    // bf16 [16][n=128][k=128]
    const int* __restrict__ bsrc, const int* __restrict__ bslot,
    const int* __restrict__ meta,
    __bf16* __restrict__ msg) {
    __shared__ __align__(16) __bf16 Bs[OUT_FEAT * 128];   // 32 KB, the only LDS
    const int* rel_off = meta;
    const int* tile_pre = meta + 32;
    int T = tile_pre[16];
    int t0 = blockIdx.x * CHUNK_T;
    if (t0 >= T) return;
    int t1 = min(T, t0 + CHUNK_T);

    int tid = threadIdx.x;
    int wave = tid >> 6, lane = tid & 63;
    int q = lane >> 4, ln = lane & 15;
    uint4* BsV = (uint4*)Bs;
    const bf16x8* BsF = (const bf16x8*)Bs;
    int myrow = wave * 16 + ln;

    int cur_rel = -1;
    for (int tt = t0; tt < t1; ++tt) {
        int rel = (cur_rel < 0) ? 0 : cur_rel;
        while (tt >= tile_pre[rel + 1]) ++rel;
        int row_start = rel_off[rel] + (tt - tile_pre[rel]) * TILE_M;
        int m_valid = min(TILE_M, rel_off[rel + 1] - row_start);

        if (rel != cur_rel) {
            if (cur_rel >= 0) __syncthreads();
            cur_rel = rel;
            const __bf16* wsrc = Wt + (size_t)rel * IN_FEAT * OUT_FEAT;
            #pragma unroll
            for (int i = 0; i < 8; ++i) {
                int cid = tid + i * 256;
                int row = cid >> 4, c = cid & 15;
                int feat = (row & 15) * 8 + (row >> 4);
                uint4 v = *(const uint4*)(wsrc + (size_t)feat * IN_FEAT + c * 8);
                BsV[row * 16 + (c ^ (row & 15))] = v;
            }
            __syncthreads();
        }

        int src = bsrc[row_start + min(myrow, m_valid - 1)];
        const __bf16* xrow = Xb + (size_t)src * IN_FEAT;
        bf16x8 afr[4];
        #pragma unroll
        for (int kk = 0; kk < 4; ++kk)
            afr[kk] = *(const bf16x8*)(xrow + (kk * 4 + q) * 8);

        int slot[4];
        #pragma unroll
        for (int reg = 0; reg < 4; ++reg) {
            int r = wave * 16 + q * 4 + reg;
            slot[reg] = (r < m_valid) ? bslot[row_start + r] : -1;
        }

        f32x4 acc[8];
        f32x4 z = { 0.f, 0.f, 0.f, 0.f };
        #pragma unroll
        for (int nf = 0; nf < 8; ++nf) acc[nf] = z;

        #pragma unroll
        for (int kk = 0; kk < 4; ++kk) {
            #pragma unroll
            for (int nf = 0; nf < 8; ++nf) {
                bf16x8 b = BsF[(nf * 16 + ln) * 16 + ((kk * 4 + q) ^ ln)];
                acc[nf] = __builtin_amdgcn_mfma_f32_16x16x32_bf16(afr[kk], b, acc[nf], 0, 0, 0);
            }
        }

        #pragma unroll
        for (int reg = 0; reg < 4; ++reg) {
            if (slot[reg] >= 0) {
                bf16x8 o = { (__bf16)acc[0][reg], (__bf16)acc[1][reg],
                             (__bf16)acc[2][reg], (__bf16)acc[3][reg],
                             (__bf16)acc[4][reg], (__bf16)acc[5][reg],
                             (__bf16)acc[6][reg], (__bf16)acc[7][reg] };
                *(bf16x8*)(msg + (size_t)slot[reg] * OUT_FEAT + ln * 8) = o;
            }
        }
    }
}

// ---------------- segment sum: 4 rows/iter, unrolled x2, fused ReLU ----------------
__global__ __launch_bounds__(256) void segsum4_kernel(
        const __bf16* __restrict__ msg, const int* __restrict__ base,
        int nnodes, int ntot, float* __restrict__ out) {
    int n = blockIdx.x * 4 + (threadIdx.x >> 6);
    if (n >= nnodes) return;
    int l = threadIdx.x & 63;
    int g = l >> 4, ln = l & 15;
    int s0 = base[n];
    int s1 = (n == nnodes - 1) ? ntot : base[n + 1];
    float a[8] = { 0.f, 0.f, 0.f, 0.f, 0.f, 0.f, 0.f, 0.f };
    for (int s = s0 + g; s < s1; s += 8) {
        bf16x8 m0 = *(const bf16x8*)(msg + (size_t)s * OUT_FEAT + ln * 8);
        if (s + 4 < s1) {
            bf16x8 m1 = *(const bf16x8*)(msg + (size_t)(s + 4) * OUT_FEAT + ln * 8);
            #pragma unroll
            for (int j = 0; j < 8; ++j) a[j] += (float)m0[j] + (float)m1[j];
        } else {
            #pragma unroll
            for (int j = 0; j < 8; ++j) a[j] += (float)m0[j];
        }
    }
    #pragma unroll
    for (int j = 0; j < 8; ++j) {
        a[j] += __shfl_xor(a[j], 16, 64);
        a[j] += __shfl_xor(a[j], 32, 64);
    }
    if (g == 0) {
        float4 o0 = { fmaxf(a[0], 0.f), fmaxf(a[1], 0.f), fmaxf(a[2], 0.f), fmaxf(a[3], 0.f) };
        float4 o1 = { fmaxf(a[4], 0.f), fmaxf(a[5], 0.f), fmaxf(a[6], 0.f), fmaxf(a[7], 0.f) };
        float* dst = out + (size_t)n * OUT_FEAT + ln * 8;
        *(float4*)dst = o0;
        *(float4*)(dst + 4) = o1;
    }
}

// ---------------- fallback path (atomic scatter GEMM + relu) ----------------
__global__ void cvtX_kernel(const float* __restrict__ x, __bf16* __restrict__ xb, int n) {
    int i = (blockIdx.x * blockDim.x + threadIdx.x) * 4;
    if (i < n) {
        float4 v = *(const float4*)(x + i);
        bf16x4 o = { (__bf16)v.x, (__bf16)v.y, (__bf16)v.z, (__bf16)v.w };
        *(bf16x4*)(xb + i) = o;
    }
}
#define LDA 136
__global__ __launch_bounds__(256) void gemm_scatter_kernel(
    const __bf16* __restrict__ Xb, const __bf16* __restrict__ Wt,
    const int* __restrict__ bsrc, const int* __restrict__ btgt,
    const int* __restrict__ meta, float* __restrict__ out) {
    __shared__ __align__(16) __bf16 As2[TILE_M * LDA];
    __shared__ __align__(16) __bf16 Bs2[OUT_FEAT * LDA];
    __shared__ int s_tgt[TILE_M];
    int bid = blockIdx.x;
    const int* rel_off = meta;
    const int* tile_pre = meta + 32;
    if (bid >= tile_pre[16]) return;
    int rel = 0;
    while (bid >= tile_pre[rel + 1]) rel++;
    int tile = bid - tile_pre[rel];
    int row_start = rel_off[rel] + tile * TILE_M;
    int m_valid = min(TILE_M, rel_off[rel + 1] - row_start);
    int t = threadIdx.x;
    {
        const __bf16* src = Wt + rel * IN_FEAT * OUT_FEAT;
        #pragma unroll
        for (int i = 0; i < 8; ++i) {
            int cid = t + i * 256;
            int n = cid >> 4, c = cid & 15;
            uint4 v = *(const uint4*)(src + n * IN_FEAT + c * 8);
            *(uint4*)(&Bs2[n * LDA + c * 8]) = v;
        }
    }
    {
        #pragma unroll
        for (int i = 0; i < 4; ++i) {
            int cid = t + i * 256;
            int r = cid >> 4, c = cid & 15;
            int srcn = (r < m_valid) ? bsrc[row_start + r] : 0;
            uint4 v = *(const uint4*)(Xb + srcn * IN_FEAT + c * 8);
            *(uint4*)(&As2[r * LDA + c * 8]) = v;
        }
        if (t < TILE_M) s_tgt[t] = (t < m_valid) ? btgt[row_start + t] : -1;
    }
    __syncthreads();
    int wave = t >> 6, lane = t & 63;
    int q = lane >> 4, ln = lane & 15;
    f32x4 acc[8];
    f32x4 z = { 0.f, 0.f, 0.f, 0.f };
    #pragma unroll
    for (int nf = 0; nf < 8; ++nf) acc[nf] = z;
    #pragma unroll
    for (int kk = 0; kk < 4; ++kk) {
        bf16x8 a = *(const bf16x8*)(&As2[(wave * 16 + ln) * LDA + kk * 32 + q * 8]);
        #pragma unroll
        for (int nf = 0; nf < 8; ++nf) {
            bf16x8 b = *(const bf16x8*)(&Bs2[(nf * 16 + ln) * LDA + kk * 32 + q * 8]);
            acc[nf] = __builtin_amdgcn_mfma_f32_16x16x32_bf16(a, b, acc[nf], 0, 0, 0);
        }
    }
    #pragma unroll
    for (int reg = 0; reg < 4; ++reg) {
        int r = wave * 16 + q * 4 + reg;
        int tgt = s_tgt[r];
        if (tgt >= 0) {
            float* orow = out + (size_t)tgt * OUT_FEAT + ln;
            #pragma unroll
            for (int nf = 0; nf < 8; ++nf)
                unsafeAtomicAdd(orow + nf * 16, acc[nf][reg]);
        }
    }
}
__global__ void relu_kernel(float* __restrict__ out, int n) {
    int i = (blockIdx.x * blockDim.x + threadIdx.x) * 4;
    if (i < n) {
        float4 v = *(float4*)(out + i);
        v.x = fmaxf(v.x, 0.f); v.y = fmaxf(v.y, 0.f);
        v.z = fmaxf(v.z, 0.f); v.w = fmaxf(v.w, 0.f);
        *(float4*)(out + i) = v;
    }
}

extern "C" void kernel_launch(void* const* d_in, const int* in_sizes, int n_in,
                              void* d_out, int out_size, void* d_ws, size_t ws_size,
                              hipStream_t stream) {
    const float* x = (const float*)d_in[0];
    const float* w = (const float*)d_in[1];
    const int* eidx = (const int*)d_in[2];
    const int* etype = (const int*)d_in[3];
    const int E = in_sizes[3];
    const int nX = in_sizes[0];
    const int N = out_size / OUT_FEAT;
    const int* esrc = eidx;
    const int* etgt = eidx + E;
    float* out = (float*)d_out;

    char* ws = (char*)d_ws;
    size_t off = 0;
    auto alloc = [&](size_t sz) { size_t o = off; off = (off + sz + 255) & ~(size_t)255; return o; };
    size_t off_Xb   = alloc((size_t)nX * 2);
    size_t off_Wt   = alloc((size_t)N_REL * IN_FEAT * OUT_FEAT * 2);
    size_t off_cnt  = alloc(64);                      // fallback rel counts
    size_t off_meta = alloc(512);
    size_t off_bsrc = alloc((size_t)E * 4);
    size_t off_bsl  = alloc((size_t)E * 4);
    size_t off_ctgt = alloc((size_t)(N + 16) * 4);    // tgt counts + rel counts (big path)
    size_t off_cur  = alloc((size_t)N * 4);
    size_t off_base = alloc((size_t)N * 4);
    size_t off_part = alloc(1024);
    size_t off_msg  = alloc((size_t)E * OUT_FEAT * 2);
    bool big = (ws_size >= off);

    __bf16* Xb = (__bf16*)(ws + off_Xb);
    __bf16* Wt = (__bf16*)(ws + off_Wt);
    int* meta  = (int*)(ws + off_meta);
    int* bsrc  = (int*)(ws + off_bsrc);
    int* bsl   = (int*)(ws + off_bsl);

    int scatter_blocks = (E + SCATTER_CHUNK - 1) / SCATTER_CHUNK;
    int max_tiles = (E + TILE_M - 1) / TILE_M + N_REL;

    if (big) {
        int* cnt_tgt = (int*)(ws + off_ctgt);
        int* cnt_rel = cnt_tgt + N;                   // adjacent -> one memset
        int* cursor  = (int*)(ws + off_cur);
        int* base    = (int*)(ws + off_base);
        __bf16* msg  = (__bf16*)(ws + off_msg);
        int nchunks = (N + 255) / 256;
        int cvtb = (nX / 8 + 255) / 256;

        hipMemsetAsync(cnt_tgt, 0, (size_t)(N + 16) * 4, stream);
        prep_kernel<<<64 + cvtb + 1024, 256, 0, stream>>>(
            w, Wt, x, Xb, nX, cvtb, etype, etgt, E, cnt_rel, cnt_tgt);
        scanC3_kernel<<<nchunks, 256, 0, stream>>>(cnt_tgt, N, cnt_rel, meta, base, cursor);
        scatter_slot_kernel<<<scatter_blocks, 256, 0, stream>>>(
            esrc, etgt, etype, E, meta + 64, cursor, bsrc, bsl);
        int gemm_blocks = (max_tiles + CHUNK_T - 1) / CHUNK_T;
        gemm_msg8_kernel<<<gemm_blocks, 256, 0, stream>>>(Xb, Wt, bsrc, bsl, meta, msg);
        segsum4_kernel<<<(N + 3) / 4, 256, 0, stream>>>(msg, base, N, E, out);
    } else {
        int* cnt = (int*)(ws + off_cnt);
        hipMemsetAsync(cnt, 0, 64, stream);
        hipMemsetAsync(out, 0, (size_t)out_size * 4, stream);
        cvtX_kernel<<<(nX / 4 + 255) / 256, 256, 0, stream>>>(x, Xb, nX);
        prep_kernel<<<64, 256, 0, stream>>>(w, Wt, x, Xb, 0, 0, etype, etgt, E, cnt, nullptr);
        hist_kernel<<<1024, 256, 0, stream>>>(etype, E, cnt);
        prefix_kernel<<<1, 64, 0, stream>>>(cnt, meta);
        scatter_kernel<<<scatter_blocks, 256, 0, stream>>>(
            esrc, etgt, etype, E, meta + 64, bsrc, bsl);
        gemm_scatter_kernel<<<max_tiles, 256, 0, stream>>>(Xb, Wt, bsrc, bsl, meta, out);
        relu_kernel<<<(out_size / 4 + 255) / 256, 256, 0, stream>>>(out, out_size);
    }
}

// Round 13
// 207.948 us; speedup vs baseline: 1.1203x; 1.1203x over previous
//
#include <hip/hip_runtime.h>
#include <hip/hip_bf16.h>

typedef __attribute__((ext_vector_type(8))) __bf16 bf16x8;
typedef __attribute__((ext_vector_type(4))) __bf16 bf16x4;
typedef __attribute__((ext_vector_type(4))) float f32x4;

#define IN_FEAT 128
#define OUT_FEAT 128
#define N_REL 16
#define TILE_M 64
#define CHUNK_T 4

// ---------------- merged prep ----------------
// blocks [0,64):          W fp32 [r][k][n] -> bf16 [r][n][k], LDS-tiled
// blocks [64,64+cvtb):    X fp32 -> bf16 (8 elems/thread, coalesced)
// blocks [64+cvtb, ...):  relation hist (LDS-agg) + target hist (direct atomics)
__global__ __launch_bounds__(256) void prep_kernel(
        const float* __restrict__ w, __bf16* __restrict__ wt,
        const float* __restrict__ x, __bf16* __restrict__ xb, int nX, int cvtb,
        const int* __restrict__ etype, const int* __restrict__ etgt, int n,
        int* __restrict__ cnt_rel, int* __restrict__ cnt_tgt) {
    __shared__ __bf16 tile[32 * 136];
    __shared__ int h[N_REL];
    int t = threadIdx.x;
    if (blockIdx.x < 64) {
        int r = blockIdx.x >> 2;
        int n0 = (blockIdx.x & 3) * 32;
        const float* W = w + (size_t)r * IN_FEAT * OUT_FEAT;
        __bf16* T = wt + (size_t)r * IN_FEAT * OUT_FEAT;
        #pragma unroll
        for (int it = 0; it < 16; ++it) {
            int idx = t + it * 256;
            int k = idx >> 5, dn = idx & 31;
            tile[dn * 136 + k] = (__bf16)W[k * OUT_FEAT + n0 + dn];
        }
        __syncthreads();
        #pragma unroll
        for (int it = 0; it < 2; ++it) {
            int idx = t + it * 256;
            int nn = idx >> 4, c = idx & 15;
            bf16x8 v = *(const bf16x8*)(&tile[nn * 136 + c * 8]);
            *(bf16x8*)(T + (size_t)(n0 + nn) * IN_FEAT + c * 8) = v;
        }
    } else if (blockIdx.x < 64 + cvtb) {
        int i = ((blockIdx.x - 64) * 256 + t) * 8;
        if (i < nX) {
            const float4* xr = (const float4*)(x + i);
            float4 f0 = xr[0], f1 = xr[1];
            bf16x8 o = { (__bf16)f0.x, (__bf16)f0.y, (__bf16)f0.z, (__bf16)f0.w,
                         (__bf16)f1.x, (__bf16)f1.y, (__bf16)f1.z, (__bf16)f1.w };
            *(bf16x8*)(xb + i) = o;
        }
    } else {
        if (t < N_REL) h[t] = 0;
        __syncthreads();
        int stride = (gridDim.x - 64 - cvtb) * blockDim.x;
        for (int i = (blockIdx.x - 64 - cvtb) * blockDim.x + t; i < n; i += stride) {
            atomicAdd(&h[etype[i]], 1);
            if (cnt_tgt) atomicAdd(&cnt_tgt[etgt[i]], 1);
        }
        __syncthreads();
        if (t < N_REL) atomicAdd(&cnt_rel[t], h[t]);
    }
}

// standalone hist + prefix (fallback path only)
__global__ void hist_kernel(const int* __restrict__ etype, int n, int* __restrict__ cnt_rel) {
    __shared__ int h[N_REL];
    if (threadIdx.x < N_REL) h[threadIdx.x] = 0;
    __syncthreads();
    for (int i = blockIdx.x * blockDim.x + threadIdx.x; i < n; i += gridDim.x * blockDim.x)
        atomicAdd(&h[etype[i]], 1);
    __syncthreads();
    if (threadIdx.x < N_REL) atomicAdd(&cnt_rel[threadIdx.x], h[threadIdx.x]);
}
__global__ void prefix_kernel(const int* __restrict__ cnt, int* __restrict__ meta) {
    if (threadIdx.x == 0) {
        int off = 0, toff = 0;
        for (int r = 0; r < N_REL; ++r) {
            meta[r] = off; meta[32 + r] = toff; meta[64 + r] = off;
            off += cnt[r];
            toff += (cnt[r] + TILE_M - 1) / TILE_M;
        }
        meta[16] = off; meta[48] = toff;
    }
}

// ---------------- 2-dispatch exclusive scan over N_NODES tgt counts (R11-proven) --------
__global__ void scanA_kernel(const int* __restrict__ cnt, int n, int* __restrict__ partial) {
    __shared__ int s[256];
    int i = blockIdx.x * 256 + threadIdx.x;
    s[threadIdx.x] = (i < n) ? cnt[i] : 0;
    __syncthreads();
    for (int off = 128; off > 0; off >>= 1) {
        if (threadIdx.x < off) s[threadIdx.x] += s[threadIdx.x + off];
        __syncthreads();
    }
    if (threadIdx.x == 0) partial[blockIdx.x] = s[0];
}
__global__ void scanC2_kernel(const int* __restrict__ cnt, int n,
                              const int* __restrict__ partial,
                              const int* __restrict__ cnt_rel, int* __restrict__ meta,
                              int* __restrict__ base, int* __restrict__ cursor) {
    __shared__ int s[256];
    __shared__ int sbase;
    int t = threadIdx.x;
    int pb = 0;
    for (int i = t; i < (int)blockIdx.x; i += 256) pb += partial[i];
    s[t] = pb;
    __syncthreads();
    for (int off = 128; off > 0; off >>= 1) {
        if (t < off) s[t] += s[t + off];
        __syncthreads();
    }
    if (t == 0) sbase = s[0];
    __syncthreads();
    int blockbase = sbase;
    __syncthreads();
    int i = blockIdx.x * 256 + t;
    int v = (i < n) ? cnt[i] : 0;
    s[t] = v;
    __syncthreads();
    for (int off = 1; off < 256; off <<= 1) {
        int x = (t >= off) ? s[t - off] : 0;
        __syncthreads();
        s[t] += x;
        __syncthreads();
    }
    int b = blockbase + s[t] - v;
    if (i < n) { base[i] = b; cursor[i] = b; }
    if (blockIdx.x == 0 && t == 0) {
        int off = 0, toff = 0;
        for (int r = 0; r < N_REL; ++r) {
            meta[r] = off; meta[32 + r] = toff; meta[64 + r] = off;
            off += cnt_rel[r];
            toff += (cnt_rel[r] + TILE_M - 1) / TILE_M;
        }
        meta[16] = off; meta[48] = toff;
    }
}

// ---------------- bucket scatter by relation, assigning tgt-sorted msg slots ----------------
#define SCATTER_EPT 2
#define SCATTER_CHUNK (256 * SCATTER_EPT)
__global__ __launch_bounds__(256) void scatter_slot_kernel(
        const int* __restrict__ esrc, const int* __restrict__ etgt,
        const int* __restrict__ etype, int n,
        int* __restrict__ cursor_rel, int* __restrict__ cursor_tgt,
        int* __restrict__ bsrc, int* __restrict__ bslot) {
    __shared__ int lcnt[N_REL];
    __shared__ int lbase[N_REL];
    int t = threadIdx.x;
    if (t < N_REL) lcnt[t] = 0;
    __syncthreads();
    int base = blockIdx.x * SCATTER_CHUNK;
    int rj[SCATTER_EPT], offj[SCATTER_EPT];
    #pragma unroll
    for (int j = 0; j < SCATTER_EPT; ++j) {
        int i = base + j * 256 + t;
        if (i < n) {
            int r = etype[i];
            rj[j] = r;
            offj[j] = atomicAdd(&lcnt[r], 1);
        } else rj[j] = -1;
    }
    __syncthreads();
    if (t < N_REL) lbase[t] = atomicAdd(&cursor_rel[t], lcnt[t]);
    __syncthreads();
    #pragma unroll
    for (int j = 0; j < SCATTER_EPT; ++j) {
        if (rj[j] >= 0) {
            int i = base + j * 256 + t;
            int p = lbase[rj[j]] + offj[j];
            bsrc[p] = esrc[i];
            bslot[p] = atomicAdd(&cursor_tgt[etgt[i]], 1);
        }
    }
}

// fallback scatter (bucket by relation, carry tgt)
__global__ __launch_bounds__(256) void scatter_kernel(
        const int* __restrict__ esrc, const int* __restrict__ etgt,
        const int* __restrict__ etype, int n,
        int* __restrict__ cursor,
        int* __restrict__ bsrc, int* __restrict__ btgt) {
    __shared__ int lcnt[N_REL];
    __shared__ int lbase[N_REL];
    int t = threadIdx.x;
    if (t < N_REL) lcnt[t] = 0;
    __syncthreads();
    int base = blockIdx.x * SCATTER_CHUNK;
    int rj[SCATTER_EPT], offj[SCATTER_EPT];
    #pragma unroll
    for (int j = 0; j < SCATTER_EPT; ++j) {
        int i = base + j * 256 + t;
        if (i < n) {
            int r = etype[i];
            rj[j] = r;
            offj[j] = atomicAdd(&lcnt[r], 1);
        } else rj[j] = -1;
    }
    __syncthreads();
    if (t < N_REL) lbase[t] = atomicAdd(&cursor[t], lcnt[t]);
    __syncthreads();
    #pragma unroll
    for (int j = 0; j < SCATTER_EPT; ++j) {
        if (rj[j] >= 0) {
            int i = base + j * 256 + t;
            int p = lbase[rj[j]] + offj[j];
            bsrc[p] = esrc[i];
            btgt[p] = etgt[i];
        }
    }
}

// ---------------- main GEMM v8 (R11): A direct-to-register, B-only LDS, barrier-free ----
// CHUNK_T 8->4: grid 979->1958 blocks. R11 showed occupancy is grid-limited (28% with
// LDS allowing 5 blocks/CU); the kernel is latency-bound on the random A-gather, so
// more co-resident blocks = more outstanding gathers + shorter tail. B restages double
// but Wt (512 KB) is L2/L3-resident.
__global__ __launch_bounds__(256, 4) void gemm_msg8_kernel(
    const __bf16* __restrict__ Xb,    // bf16 [N_NODES][128]
    const __bf16* __restrict__ Wt,    // bf16 [16][n=128][k=128]
    const int* __restrict__ bsrc, const int* __restrict__ bslot,
    const int* __restrict__ meta,
    __bf16* __restrict__ msg) {
    __shared__ __align__(16) __bf16 Bs[OUT_FEAT * 128];   // 32 KB, the only LDS
    const int* rel_off = meta;
    const int* tile_pre = meta + 32;
    int T = tile_pre[16];
    int t0 = blockIdx.x * CHUNK_T;
    if (t0 >= T) return;
    int t1 = min(T, t0 + CHUNK_T);

    int tid = threadIdx.x;
    int wave = tid >> 6, lane = tid & 63;
    int q = lane >> 4, ln = lane & 15;
    uint4* BsV = (uint4*)Bs;
    const bf16x8* BsF = (const bf16x8*)Bs;
    int myrow = wave * 16 + ln;

    int cur_rel = -1;
    for (int tt = t0; tt < t1; ++tt) {
        int rel = (cur_rel < 0) ? 0 : cur_rel;
        while (tt >= tile_pre[rel + 1]) ++rel;
        int row_start = rel_off[rel] + (tt - tile_pre[rel]) * TILE_M;
        int m_valid = min(TILE_M, rel_off[rel + 1] - row_start);

        if (rel != cur_rel) {
            if (cur_rel >= 0) __syncthreads();
            cur_rel = rel;
            const __bf16* wsrc = Wt + (size_t)rel * IN_FEAT * OUT_FEAT;
            #pragma unroll
            for (int i = 0; i < 8; ++i) {
                int cid = tid + i * 256;
                int row = cid >> 4, c = cid & 15;
                int feat = (row & 15) * 8 + (row >> 4);   // feature permutation
                uint4 v = *(const uint4*)(wsrc + (size_t)feat * IN_FEAT + c * 8);
                BsV[row * 16 + (c ^ (row & 15))] = v;
            }
            __syncthreads();
        }

        // A fragments: direct global gather into registers
        int src = bsrc[row_start + min(myrow, m_valid - 1)];
        const __bf16* xrow = Xb + (size_t)src * IN_FEAT;
        bf16x8 afr[4];
        #pragma unroll
        for (int kk = 0; kk < 4; ++kk)
            afr[kk] = *(const bf16x8*)(xrow + (kk * 4 + q) * 8);

        // slots for the 4 rows this lane will store (wave-uniform across ln)
        int slot[4];
        #pragma unroll
        for (int reg = 0; reg < 4; ++reg) {
            int r = wave * 16 + q * 4 + reg;
            slot[reg] = (r < m_valid) ? bslot[row_start + r] : -1;
        }

        f32x4 acc[8];
        f32x4 z = { 0.f, 0.f, 0.f, 0.f };
        #pragma unroll
        for (int nf = 0; nf < 8; ++nf) acc[nf] = z;

        #pragma unroll
        for (int kk = 0; kk < 4; ++kk) {
            #pragma unroll
            for (int nf = 0; nf < 8; ++nf) {
                bf16x8 b = BsF[(nf * 16 + ln) * 16 + ((kk * 4 + q) ^ ln)];
                // C[row = wave*16+q*4+reg -> msg row][col = ln -> features ln*8..+7]
                acc[nf] = __builtin_amdgcn_mfma_f32_16x16x32_bf16(afr[kk], b, acc[nf], 0, 0, 0);
            }
        }

        // direct epilogue: one bf16x8 (16 B) store per C-row; a q-group's 16 lanes
        // cover one full 256 B msg row contiguously.
        #pragma unroll
        for (int reg = 0; reg < 4; ++reg) {
            if (slot[reg] >= 0) {
                bf16x8 o = { (__bf16)acc[0][reg], (__bf16)acc[1][reg],
                             (__bf16)acc[2][reg], (__bf16)acc[3][reg],
                             (__bf16)acc[4][reg], (__bf16)acc[5][reg],
                             (__bf16)acc[6][reg], (__bf16)acc[7][reg] };
                *(bf16x8*)(msg + (size_t)slot[reg] * OUT_FEAT + ln * 8) = o;
            }
        }
    }
}

// ---------------- segment sum: 4 rows/iter, unrolled x2, fused ReLU ----------------
__global__ __launch_bounds__(256) void segsum4_kernel(
        const __bf16* __restrict__ msg, const int* __restrict__ base,
        int nnodes, int ntot, float* __restrict__ out) {
    int n = blockIdx.x * 4 + (threadIdx.x >> 6);
    if (n >= nnodes) return;
    int l = threadIdx.x & 63;
    int g = l >> 4, ln = l & 15;
    int s0 = base[n];
    int s1 = (n == nnodes - 1) ? ntot : base[n + 1];
    float a[8] = { 0.f, 0.f, 0.f, 0.f, 0.f, 0.f, 0.f, 0.f };
    for (int s = s0 + g; s < s1; s += 8) {
        bf16x8 m0 = *(const bf16x8*)(msg + (size_t)s * OUT_FEAT + ln * 8);
        if (s + 4 < s1) {
            bf16x8 m1 = *(const bf16x8*)(msg + (size_t)(s + 4) * OUT_FEAT + ln * 8);
            #pragma unroll
            for (int j = 0; j < 8; ++j) a[j] += (float)m0[j] + (float)m1[j];
        } else {
            #pragma unroll
            for (int j = 0; j < 8; ++j) a[j] += (float)m0[j];
        }
    }
    #pragma unroll
    for (int j = 0; j < 8; ++j) {
        a[j] += __shfl_xor(a[j], 16, 64);
        a[j] += __shfl_xor(a[j], 32, 64);
    }
    if (g == 0) {
        float4 o0 = { fmaxf(a[0], 0.f), fmaxf(a[1], 0.f), fmaxf(a[2], 0.f), fmaxf(a[3], 0.f) };
        float4 o1 = { fmaxf(a[4], 0.f), fmaxf(a[5], 0.f), fmaxf(a[6], 0.f), fmaxf(a[7], 0.f) };
        float* dst = out + (size_t)n * OUT_FEAT + ln * 8;
        *(float4*)dst = o0;
        *(float4*)(dst + 4) = o1;
    }
}

// ---------------- fallback path (atomic scatter GEMM + relu) ----------------
__global__ void cvtX_kernel(const float* __restrict__ x, __bf16* __restrict__ xb, int n) {
    int i = (blockIdx.x * blockDim.x + threadIdx.x) * 4;
    if (i < n) {
        float4 v = *(const float4*)(x + i);
        bf16x4 o = { (__bf16)v.x, (__bf16)v.y, (__bf16)v.z, (__bf16)v.w };
        *(bf16x4*)(xb + i) = o;
    }
}
#define LDA 136
__global__ __launch_bounds__(256) void gemm_scatter_kernel(
    const __bf16* __restrict__ Xb, const __bf16* __restrict__ Wt,
    const int* __restrict__ bsrc, const int* __restrict__ btgt,
    const int* __restrict__ meta, float* __restrict__ out) {
    __shared__ __align__(16) __bf16 As2[TILE_M * LDA];
    __shared__ __align__(16) __bf16 Bs2[OUT_FEAT * LDA];
    __shared__ int s_tgt[TILE_M];
    int bid = blockIdx.x;
    const int* rel_off = meta;
    const int* tile_pre = meta + 32;
    if (bid >= tile_pre[16]) return;
    int rel = 0;
    while (bid >= tile_pre[rel + 1]) rel++;
    int tile = bid - tile_pre[rel];
    int row_start = rel_off[rel] + tile * TILE_M;
    int m_valid = min(TILE_M, rel_off[rel + 1] - row_start);
    int t = threadIdx.x;
    {
        const __bf16* src = Wt + rel * IN_FEAT * OUT_FEAT;
        #pragma unroll
        for (int i = 0; i < 8; ++i) {
            int cid = t + i * 256;
            int n = cid >> 4, c = cid & 15;
            uint4 v = *(const uint4*)(src + n * IN_FEAT + c * 8);
            *(uint4*)(&Bs2[n * LDA + c * 8]) = v;
        }
    }
    {
        #pragma unroll
        for (int i = 0; i < 4; ++i) {
            int cid = t + i * 256;
            int r = cid >> 4, c = cid & 15;
            int srcn = (r < m_valid) ? bsrc[row_start + r] : 0;
            uint4 v = *(const uint4*)(Xb + srcn * IN_FEAT + c * 8);
            *(uint4*)(&As2[r * LDA + c * 8]) = v;
        }
        if (t < TILE_M) s_tgt[t] = (t < m_valid) ? btgt[row_start + t] : -1;
    }
    __syncthreads();
    int wave = t >> 6, lane = t & 63;
    int q = lane >> 4, ln = lane & 15;
    f32x4 acc[8];
    f32x4 z = { 0.f, 0.f, 0.f, 0.f };
    #pragma unroll
    for (int nf = 0; nf < 8; ++nf) acc[nf] = z;
    #pragma unroll
    for (int kk = 0; kk < 4; ++kk) {
        bf16x8 a = *(const bf16x8*)(&As2[(wave * 16 + ln) * LDA + kk * 32 + q * 8]);
        #pragma unroll
        for (int nf = 0; nf < 8; ++nf) {
            bf16x8 b = *(const bf16x8*)(&Bs2[(nf * 16 + ln) * LDA + kk * 32 + q * 8]);
            acc[nf] = __builtin_amdgcn_mfma_f32_16x16x32_bf16(a, b, acc[nf], 0, 0, 0);
        }
    }
    #pragma unroll
    for (int reg = 0; reg < 4; ++reg) {
        int r = wave * 16 + q * 4 + reg;
        int tgt = s_tgt[r];
        if (tgt >= 0) {
            float* orow = out + (size_t)tgt * OUT_FEAT + ln;
            #pragma unroll
            for (int nf = 0; nf < 8; ++nf)
                unsafeAtomicAdd(orow + nf * 16, acc[nf][reg]);
        }
    }
}
__global__ void relu_kernel(float* __restrict__ out, int n) {
    int i = (blockIdx.x * blockDim.x + threadIdx.x) * 4;
    if (i < n) {
        float4 v = *(float4*)(out + i);
        v.x = fmaxf(v.x, 0.f); v.y = fmaxf(v.y, 0.f);
        v.z = fmaxf(v.z, 0.f); v.w = fmaxf(v.w, 0.f);
        *(float4*)(out + i) = v;
    }
}

extern "C" void kernel_launch(void* const* d_in, const int* in_sizes, int n_in,
                              void* d_out, int out_size, void* d_ws, size_t ws_size,
                              hipStream_t stream) {
    const float* x = (const float*)d_in[0];
    const float* w = (const float*)d_in[1];
    const int* eidx = (const int*)d_in[2];
    const int* etype = (const int*)d_in[3];
    const int E = in_sizes[3];
    const int nX = in_sizes[0];
    const int N = out_size / OUT_FEAT;
    const int* esrc = eidx;
    const int* etgt = eidx + E;
    float* out = (float*)d_out;

    char* ws = (char*)d_ws;
    size_t off = 0;
    auto alloc = [&](size_t sz) { size_t o = off; off = (off + sz + 255) & ~(size_t)255; return o; };
    size_t off_Xb   = alloc((size_t)nX * 2);
    size_t off_Wt   = alloc((size_t)N_REL * IN_FEAT * OUT_FEAT * 2);
    size_t off_cnt  = alloc(64);                      // fallback rel counts
    size_t off_meta = alloc(512);
    size_t off_bsrc = alloc((size_t)E * 4);
    size_t off_bsl  = alloc((size_t)E * 4);
    size_t off_ctgt = alloc((size_t)(N + 16) * 4);    // tgt counts + rel counts (big path)
    size_t off_cur  = alloc((size_t)N * 4);
    size_t off_base = alloc((size_t)N * 4);
    size_t off_part = alloc(1024);
    size_t off_msg  = alloc((size_t)E * OUT_FEAT * 2);
    bool big = (ws_size >= off);

    __bf16* Xb = (__bf16*)(ws + off_Xb);
    __bf16* Wt = (__bf16*)(ws + off_Wt);
    int* meta  = (int*)(ws + off_meta);
    int* bsrc  = (int*)(ws + off_bsrc);
    int* bsl   = (int*)(ws + off_bsl);

    int scatter_blocks = (E + SCATTER_CHUNK - 1) / SCATTER_CHUNK;
    int max_tiles = (E + TILE_M - 1) / TILE_M + N_REL;

    if (big) {
        int* cnt_tgt = (int*)(ws + off_ctgt);
        int* cnt_rel = cnt_tgt + N;                   // adjacent -> one memset
        int* cursor  = (int*)(ws + off_cur);
        int* base    = (int*)(ws + off_base);
        int* partial = (int*)(ws + off_part);
        __bf16* msg  = (__bf16*)(ws + off_msg);
        int nchunks = (N + 255) / 256;
        int cvtb = (nX / 8 + 255) / 256;

        hipMemsetAsync(cnt_tgt, 0, (size_t)(N + 16) * 4, stream);
        prep_kernel<<<64 + cvtb + 1024, 256, 0, stream>>>(
            w, Wt, x, Xb, nX, cvtb, etype, etgt, E, cnt_rel, cnt_tgt);
        scanA_kernel<<<nchunks, 256, 0, stream>>>(cnt_tgt, N, partial);
        scanC2_kernel<<<nchunks, 256, 0, stream>>>(cnt_tgt, N, partial, cnt_rel, meta, base, cursor);
        scatter_slot_kernel<<<scatter_blocks, 256, 0, stream>>>(
            esrc, etgt, etype, E, meta + 64, cursor, bsrc, bsl);
        int gemm_blocks = (max_tiles + CHUNK_T - 1) / CHUNK_T;
        gemm_msg8_kernel<<<gemm_blocks, 256, 0, stream>>>(Xb, Wt, bsrc, bsl, meta, msg);
        segsum4_kernel<<<(N + 3) / 4, 256, 0, stream>>>(msg, base, N, E, out);
    } else {
        int* cnt = (int*)(ws + off_cnt);
        hipMemsetAsync(cnt, 0, 64, stream);
        hipMemsetAsync(out, 0, (size_t)out_size * 4, stream);
        cvtX_kernel<<<(nX / 4 + 255) / 256, 256, 0, stream>>>(x, Xb, nX);
        prep_kernel<<<64, 256, 0, stream>>>(w, Wt, x, Xb, 0, 0, etype, etgt, E, cnt, nullptr);
        hist_kernel<<<1024, 256, 0, stream>>>(etype, E, cnt);
        prefix_kernel<<<1, 64, 0, stream>>>(cnt, meta);
        scatter_kernel<<<scatter_blocks, 256, 0, stream>>>(
            esrc, etgt, etype, E, meta + 64, bsrc, bsl);
        gemm_scatter_kernel<<<max_tiles, 256, 0, stream>>>(Xb, Wt, bsrc, bsl, meta, out);
        relu_kernel<<<(out_size / 4 + 255) / 256, 256, 0, stream>>>(out, out_size);
    }
}